// Round 7
// baseline (811.624 us; speedup 1.0000x reference)
//
#include <hip/hip_runtime.h>

typedef unsigned short ushort_t;
typedef unsigned int uint_t;

#define N_NODES 50000
#define N_EDGES 800000
#define IN_DIM 96
#define OUT_DIM 96
#define EDGE_DIM 32
#define BN_EPS 1e-5f

// ws layout (4-byte words), tier-1 (sorted bf16 msg):
//   [0 .. 4800000)            h buffer -> reused as h2
//   [4800000 .. 4800192)      BN stats
//   [4800192]                 edge_index-dtype flag (1 = int64)
//   [4800256 .. 4850256)      counts  (50000 int)
//   [4850256 .. 4900272)      rowptr  (50001 int, padded)
//   [4900272 .. 4950272)      cursor  (50000 int)
//   [4950272 .. 43350272)     msg_sorted (76.8M bf16 = 38.4M words)
#define OFF_STATS  4800000
#define OFF_FLAG   4800192
#define OFF_COUNTS 4800256
#define OFF_ROWPTR 4850256
#define OFF_CURSOR 4900272
#define OFF_MSG    4950272
#define WS_REQ_NEW ((size_t)43350272 * 4)
#define WS_REQ_OLD ((size_t)(OFF_FLAG + 64) * 4)

__device__ __forceinline__ float bflo(uint_t u) { return __uint_as_float(u << 16); }
__device__ __forceinline__ float bfhi(uint_t u) { return __uint_as_float(u & 0xffff0000u); }
__device__ __forceinline__ ushort_t f2bf(float f) {
    uint_t u = __float_as_uint(f);
    uint_t r = ((u >> 16) & 1u) + 0x7fffu;  // RNE
    return (ushort_t)((u + r) >> 16);
}

// ---------------------------------------------------------------------------
// detect: int64 vs int32 edge_index. int64 (<50000) => all odd int32 words 0.
// 4096 samples, all < 1.6M (valid under either layout).
// ---------------------------------------------------------------------------
__global__ __launch_bounds__(1024) void detect_kernel(const int* __restrict__ ei,
                                                      int* __restrict__ flag) {
    __shared__ int any_nonzero;
    if (threadIdx.x == 0) any_nonzero = 0;
    __syncthreads();
    int nz = 0;
#pragma unroll
    for (int q = 0; q < 4; ++q) {
        int p = 1 + 2 * (threadIdx.x * 4 + q) * 195;  // odd, <= 1,598,051
        if (ei[p] != 0) nz = 1;
    }
    if (nz) atomicOr(&any_nonzero, 1);
    __syncthreads();
    if (threadIdx.x == 0) *flag = any_nonzero ? 0 : 1;
}

__device__ __forceinline__ void load_edge(const int* __restrict__ ei, int e,
                                          int is64, int& s, int& d) {
    if (is64) { s = ei[2 * e]; d = ei[2 * N_EDGES + 2 * e]; }
    else      { s = ei[e];     d = ei[N_EDGES + e]; }
}

// ---------------------------------------------------------------------------
// hist -> scan (rowptr, cursor)
// ---------------------------------------------------------------------------
__global__ __launch_bounds__(256) void hist_kernel(const int* __restrict__ ei,
                                                   int* __restrict__ counts,
                                                   const int* __restrict__ flag) {
    const int is64 = *flag;
    for (int e = blockIdx.x * blockDim.x + threadIdx.x; e < N_EDGES;
         e += gridDim.x * blockDim.x) {
        int s, d;
        load_edge(ei, e, is64, s, d);
        if (s >= 0 && s < N_NODES && d >= 0 && d < N_NODES)
            atomicAdd(&counts[d], 1);
    }
}

#define SCAN_T 1024
#define SCAN_C 49  // 1024*49 >= 50000
__global__ __launch_bounds__(SCAN_T) void scan_kernel(
    const int* __restrict__ counts, int* __restrict__ rowptr,
    int* __restrict__ cursor) {
    __shared__ int ps[SCAN_T];
    const int t = threadIdx.x;
    const int lo = t * SCAN_C;
    const int hi = (lo + SCAN_C < N_NODES) ? lo + SCAN_C : N_NODES;
    int s = 0;
    for (int i = lo; i < hi; ++i) s += counts[i];
    ps[t] = s;
    __syncthreads();
    for (int off = 1; off < SCAN_T; off <<= 1) {
        int v = ps[t];
        int u = (t >= off) ? ps[t - off] : 0;
        __syncthreads();
        ps[t] = v + u;
        __syncthreads();
    }
    int run = ps[t] - s;
    for (int i = lo; i < hi; ++i) {
        rowptr[i] = run;
        cursor[i] = run;
        run += counts[i];
    }
    if (t == SCAN_T - 1) rowptr[N_NODES] = ps[SCAN_T - 1];
}

// ---------------------------------------------------------------------------
// msg_kernel: edge-parallel projection + relu, written DST-SORTED as bf16.
// Block = 4 slots x 96 threads; thread j holds We column j in registers.
// One cursor atomic per edge (thread j==0), pos shared via LDS.
// msg row = 96 bf16 = 192 B, coalesced (thread j writes ushort j).
// ---------------------------------------------------------------------------
#define ESLOTS 4
#define EBLOCK (ESLOTS * 96)

__global__ __launch_bounds__(EBLOCK) void msg_kernel(
    const float* __restrict__ x, const int* __restrict__ ei,
    const float* __restrict__ ea, const float* __restrict__ We,
    const float* __restrict__ be, int* __restrict__ cursor,
    ushort_t* __restrict__ msg, const int* __restrict__ flag) {
    const int tid = threadIdx.x;
    const int slot = tid / 96;
    const int j = tid - slot * 96;
    const int is64 = *flag;

    float w[EDGE_DIM];
#pragma unroll
    for (int k = 0; k < EDGE_DIM; ++k) w[k] = We[k * 96 + j];
    const float bej = be[j];

    __shared__ float ea_s[ESLOTS][EDGE_DIM];
    __shared__ int pos_s[ESLOTS];

    for (long e0 = (long)blockIdx.x * ESLOTS; e0 < N_EDGES;
         e0 += (long)gridDim.x * ESLOTS) {
        const int e = (int)e0 + slot;
        const bool valid = (e < N_EDGES);
        int s = -1, d = -1;
        if (valid) load_edge(ei, e, is64, s, d);
        const bool inr = valid && s >= 0 && s < N_NODES && d >= 0 && d < N_NODES;
        if (valid && j < EDGE_DIM) ea_s[slot][j] = ea[e * EDGE_DIM + j];
        if (inr && j == 0) pos_s[slot] = atomicAdd(&cursor[d], 1);
        __syncthreads();
        if (inr) {
            float acc = bej;
#pragma unroll
            for (int k = 0; k < EDGE_DIM; ++k) acc += ea_s[slot][k] * w[k];
            float m = acc + x[(size_t)s * 96 + j];
            m = m > 0.f ? m : 0.f;
            msg[(size_t)pos_s[slot] * 96 + j] = f2bf(m);
        }
        __syncthreads();
    }
}

// ---------------------------------------------------------------------------
// segsum: one wave per node. Rows for node n are CONTIGUOUS (sorted) ->
// streaming loads, addresses independent of loaded data. Lane l<48 sums
// uint-packed bf16 pair (2l, 2l+1). Writes h = x + aggr.
// ---------------------------------------------------------------------------
__global__ __launch_bounds__(256) void segsum_kernel(
    const float* __restrict__ x, const ushort_t* __restrict__ msg,
    const int* __restrict__ rowptr, float* __restrict__ h) {
    const int lane = threadIdx.x & 63;
    const int wid = threadIdx.x >> 6;
    const uint_t* m32 = (const uint_t*)msg;

    const int nw = gridDim.x * 4;
    for (int n = blockIdx.x * 4 + wid; n < N_NODES; n += nw) {
        const int beg = rowptr[n];
        const int end = rowptr[n + 1];
        if (lane < 48) {
            float a0 = 0.f, a1 = 0.f;
            for (int i = beg; i < end; ++i) {
                uint_t u = m32[(size_t)i * 48 + lane];
                a0 += bflo(u);
                a1 += bfhi(u);
            }
            const size_t b = (size_t)n * 96 + lane * 2;
            h[b] = x[b] + a0;
            h[b + 1] = x[b + 1] + a1;
        }
    }
}

// ---------------------------------------------------------------------------
// Fallback (small ws): R5 atomic scatter-add edge kernel.
// ---------------------------------------------------------------------------
__global__ __launch_bounds__(EBLOCK) void edge_kernel(
    const float* __restrict__ x, const int* __restrict__ ei,
    const float* __restrict__ ea, const float* __restrict__ We,
    const float* __restrict__ be, float* __restrict__ aggr,
    const int* __restrict__ flag) {
    const int tid = threadIdx.x;
    const int slot = tid / 96;
    const int j = tid - slot * 96;
    const int is64 = *flag;
    float w[EDGE_DIM];
#pragma unroll
    for (int k = 0; k < EDGE_DIM; ++k) w[k] = We[k * 96 + j];
    const float bej = be[j];
    __shared__ float ea_s[ESLOTS][EDGE_DIM];
    for (long e0 = (long)blockIdx.x * ESLOTS; e0 < N_EDGES;
         e0 += (long)gridDim.x * ESLOTS) {
        const int e = (int)e0 + slot;
        const bool valid = (e < N_EDGES);
        if (valid && j < EDGE_DIM) ea_s[slot][j] = ea[e * EDGE_DIM + j];
        __syncthreads();
        if (valid) {
            float acc = bej;
#pragma unroll
            for (int k = 0; k < EDGE_DIM; ++k) acc += ea_s[slot][k] * w[k];
            int s, d;
            load_edge(ei, e, is64, s, d);
            if (s >= 0 && s < N_NODES && d >= 0 && d < N_NODES) {
                float m = acc + x[s * 96 + j];
                m = m > 0.f ? m : 0.f;
                atomicAdd(&aggr[d * 96 + j], m);
            }
        }
        __syncthreads();
    }
}

// ---------------------------------------------------------------------------
// Node MLP (fp32). 32-node tile, 256 threads. buf = h (addx=0) or aggr
// (addx=1). Writes o back into same buffer (disjoint rows; staged via LDS).
// BN partials -> global atomics.
// ---------------------------------------------------------------------------
__global__ __launch_bounds__(256) void mlp_kernel(
    const float* __restrict__ x, const float* buf, int addx,
    const float* __restrict__ W1g, const float* __restrict__ b1g,
    const float* __restrict__ W2g, const float* __restrict__ b2g,
    float* h2, float* __restrict__ stats) {
    __shared__ float Ws[96 * 96];
    __shared__ float hs[32][97];
    __shared__ float os[32][97];
    __shared__ float b1s[96], b2s[96];

    const int tid = threadIdx.x;
    const int n0 = blockIdx.x * 32;

    for (int i = tid; i < 96 * 96; i += 256) Ws[i] = W1g[i];
    if (tid < 96) {
        b1s[tid] = b1g[tid];
        b2s[tid] = b2g[tid];
    }
    for (int i = tid; i < 32 * 96; i += 256) {
        int n = i / 96, k = i - n * 96;
        float v = 0.f;
        if (n0 + n < N_NODES) {
            int idx = (n0 + n) * 96 + k;
            v = buf[idx];
            if (addx) v += x[idx];
        }
        hs[n][k] = v;
    }
    __syncthreads();

    const int n = tid >> 3;
    const int jg = tid & 7;
    float acc[12];

#pragma unroll
    for (int m = 0; m < 12; ++m) acc[m] = b1s[jg * 12 + m];
    for (int k = 0; k < 96; ++k) {
        float hv = hs[n][k];
#pragma unroll
        for (int m = 0; m < 12; ++m) acc[m] += hv * Ws[k * 96 + jg * 12 + m];
    }
#pragma unroll
    for (int m = 0; m < 12; ++m)
        os[n][jg * 12 + m] = acc[m] > 0.f ? acc[m] : 0.f;
    __syncthreads();

    for (int i = tid; i < 96 * 96; i += 256) Ws[i] = W2g[i];
    __syncthreads();

#pragma unroll
    for (int m = 0; m < 12; ++m) acc[m] = b2s[jg * 12 + m];
    for (int k = 0; k < 96; ++k) {
        float hv = os[n][k];
#pragma unroll
        for (int m = 0; m < 12; ++m) acc[m] += hv * Ws[k * 96 + jg * 12 + m];
    }
#pragma unroll
    for (int m = 0; m < 12; ++m) hs[n][jg * 12 + m] = acc[m];
    __syncthreads();

    for (int i = tid; i < 32 * 96; i += 256) {
        int nn = i / 96, k = i - nn * 96;
        if (n0 + nn < N_NODES) h2[(n0 + nn) * 96 + k] = hs[nn][k];
    }
    if (tid < 96) {
        float s = 0.f, s2 = 0.f;
        int nmax = N_NODES - n0;
        if (nmax > 32) nmax = 32;
        for (int nn = 0; nn < nmax; ++nn) {
            float v = hs[nn][tid];
            s += v;
            s2 += v * v;
        }
        atomicAdd(&stats[tid], s);
        atomicAdd(&stats[96 + tid], s2);
    }
}

// ---------------------------------------------------------------------------
// BN finalize + affine + ReLU -> fp32 out.
// ---------------------------------------------------------------------------
__global__ __launch_bounds__(256) void bn_kernel(
    const float* __restrict__ h2, const float* __restrict__ stats,
    const float* __restrict__ gamma, const float* __restrict__ beta,
    float* __restrict__ out) {
    __shared__ float sc[96], sh[96];
    const int tid = threadIdx.x;
    if (tid < 96) {
        const float inv_n = 1.f / (float)N_NODES;
        float mean = stats[tid] * inv_n;
        float var = stats[96 + tid] * inv_n - mean * mean;
        var = var > 0.f ? var : 0.f;
        float s = gamma[tid] * rsqrtf(var + BN_EPS);
        sc[tid] = s;
        sh[tid] = beta[tid] - mean * s;
    }
    __syncthreads();
    const int total = N_NODES * 96;
    for (int i = blockIdx.x * blockDim.x + tid; i < total;
         i += gridDim.x * blockDim.x) {
        int j = i % 96;
        float v = h2[i] * sc[j] + sh[j];
        out[i] = v > 0.f ? v : 0.f;
    }
}

// ---------------------------------------------------------------------------
extern "C" void kernel_launch(void* const* d_in, const int* in_sizes, int n_in,
                              void* d_out, int out_size, void* d_ws,
                              size_t ws_size, hipStream_t stream) {
    const float* x     = (const float*)d_in[0];
    const int*   ei    = (const int*)d_in[1];
    const float* ea    = (const float*)d_in[2];
    const float* We    = (const float*)d_in[3];
    const float* be    = (const float*)d_in[4];
    const float* W1    = (const float*)d_in[5];
    const float* b1    = (const float*)d_in[6];
    const float* W2    = (const float*)d_in[7];
    const float* b2    = (const float*)d_in[8];
    const float* gamma = (const float*)d_in[9];
    const float* beta  = (const float*)d_in[10];
    float* out = (float*)d_out;

    float*    ws     = (float*)d_ws;
    float*    hbuf   = ws;
    float*    stats  = ws + OFF_STATS;
    int*      flag   = (int*)(ws + OFF_FLAG);
    int*      counts = (int*)(ws + OFF_COUNTS);
    int*      rowptr = (int*)(ws + OFF_ROWPTR);
    int*      cursor = (int*)(ws + OFF_CURSOR);
    ushort_t* msg    = (ushort_t*)(ws + OFF_MSG);

    if (ws_size >= WS_REQ_NEW) {
        // zero stats + flag + counts (~201 KB); h / msg fully overwritten
        hipMemsetAsync((void*)stats, 0,
                       (size_t)(OFF_COUNTS + N_NODES - OFF_STATS) * 4, stream);
        detect_kernel<<<1, 1024, 0, stream>>>(ei, flag);
        hist_kernel<<<1024, 256, 0, stream>>>(ei, counts, flag);
        scan_kernel<<<1, SCAN_T, 0, stream>>>(counts, rowptr, cursor);
        msg_kernel<<<2048, EBLOCK, 0, stream>>>(x, ei, ea, We, be, cursor, msg,
                                                flag);
        segsum_kernel<<<2048, 256, 0, stream>>>(x, msg, rowptr, hbuf);
        mlp_kernel<<<(N_NODES + 31) / 32, 256, 0, stream>>>(
            x, hbuf, /*addx=*/0, W1, b1, W2, b2, /*h2=*/hbuf, stats);
    } else {
        size_t zbytes = WS_REQ_OLD;
        if (zbytes > ws_size) zbytes = ws_size;
        hipMemsetAsync(d_ws, 0, zbytes, stream);
        detect_kernel<<<1, 1024, 0, stream>>>(ei, flag);
        edge_kernel<<<2048, EBLOCK, 0, stream>>>(x, ei, ea, We, be, hbuf, flag);
        mlp_kernel<<<(N_NODES + 31) / 32, 256, 0, stream>>>(
            x, hbuf, /*addx=*/1, W1, b1, W2, b2, /*h2=*/hbuf, stats);
    }
    bn_kernel<<<512, 256, 0, stream>>>(hbuf, stats, gamma, beta, out);
}

// Round 8
// 488.118 us; speedup vs baseline: 1.6628x; 1.6628x over previous
//
#include <hip/hip_runtime.h>

typedef unsigned short ushort_t;
typedef unsigned int uint_t;
typedef __attribute__((ext_vector_type(8))) short bf16x8;
typedef __attribute__((ext_vector_type(4))) float f32x4;
typedef __attribute__((ext_vector_type(2))) float f32x2;

#define N_NODES 50000
#define N_EDGES 800000
#define BN_EPS 1e-5f

// ws layout (floats): [0 .. 4800000) h buffer (init=x, edge adds msgs, mlp
//                     overwrites with o rows)   [4800000..4800192) BN stats
//                     [4800192] edge_index dtype flag (1 = int64)
#define OFF_STATS 4800000
#define OFF_FLAG  4800192

__device__ __forceinline__ ushort_t f2bf(float f) {
    uint_t u = __float_as_uint(f);
    uint_t r = ((u >> 16) & 1u) + 0x7fffu;  // RNE
    return (ushort_t)((u + r) >> 16);
}

// ---------------------------------------------------------------------------
// detect: int64 vs int32 edge_index. int64 data (<50000) => every odd int32
// word is 0. 4096 samples, all < 1.6M (in-bounds under either layout).
// ---------------------------------------------------------------------------
__global__ __launch_bounds__(1024) void detect_kernel(const int* __restrict__ ei,
                                                      int* __restrict__ flag) {
    __shared__ int any_nonzero;
    if (threadIdx.x == 0) any_nonzero = 0;
    __syncthreads();
    int nz = 0;
#pragma unroll
    for (int q = 0; q < 4; ++q) {
        int p = 1 + 2 * (threadIdx.x * 4 + q) * 195;  // odd, <= 1,598,051
        if (ei[p] != 0) nz = 1;
    }
    if (nz) atomicOr(&any_nonzero, 1);
    __syncthreads();
    if (threadIdx.x == 0) *flag = any_nonzero ? 0 : 1;
}

// ---------------------------------------------------------------------------
// edge_mfma: one wave per 16-edge tile.
//   proj[16e x 96f] = ea_tile[16 x 32] @ We[32 x 96] via 6x mfma 16x16x32 bf16
//   A-frag: lane(q,t): A[m=t][k=q*8+j] -> ea row e0+t, 8 floats at k=q*8,
//           loaded straight from global (2x b128) and cvt to bf16. No LDS.
//   B-frags: B[k=q*8+j][n=t+16f] held in VGPRs for kernel lifetime.
//   C/D: row m=q*4+r (edge), col n=t (feature within block)  [m89 layout]
//   Epilogue: m = relu(proj + be + x[src]); atomicAdd into aggr[dst] (aggr
//   pre-initialized to x, so it accumulates h = x + sum(msg)).
// ---------------------------------------------------------------------------
__global__ __launch_bounds__(256) void edge_mfma_kernel(
    const float* __restrict__ x, const int* __restrict__ ei,
    const float* __restrict__ ea, const float* __restrict__ We,
    const float* __restrict__ be, float* __restrict__ aggr,
    const int* __restrict__ flag) {
    const int lane = threadIdx.x & 63;
    const int wav = blockIdx.x * (blockDim.x >> 6) + (threadIdx.x >> 6);
    const int nwav = gridDim.x * (blockDim.x >> 6);
    const int is64 = *flag;
    const int q = lane >> 4;   // quad 0..3
    const int t = lane & 15;   // 0..15

    bf16x8 Bf[6];
    float ben[6];
#pragma unroll
    for (int f = 0; f < 6; ++f) {
        const int n = t + 16 * f;
#pragma unroll
        for (int j = 0; j < 8; ++j) {
            const int k = q * 8 + j;
            Bf[f][j] = (short)f2bf(We[k * 96 + n]);
        }
        ben[f] = be[n];
    }

    for (int tile = wav; tile < N_EDGES / 16; tile += nwav) {
        const int e0 = tile * 16;
        const float* row = ea + (size_t)(e0 + t) * 32 + q * 8;
        f32x4 a0 = *(const f32x4*)(row);
        f32x4 a1 = *(const f32x4*)(row + 4);
        bf16x8 A;
#pragma unroll
        for (int j = 0; j < 4; ++j) {
            A[j] = (short)f2bf(a0[j]);
            A[4 + j] = (short)f2bf(a1[j]);
        }

        f32x4 acc[6];
#pragma unroll
        for (int f = 0; f < 6; ++f) {
            f32x4 z = {0.f, 0.f, 0.f, 0.f};
            acc[f] = __builtin_amdgcn_mfma_f32_16x16x32_bf16(A, Bf[f], z, 0, 0, 0);
        }

        int srcs[4], dsts[4];
#pragma unroll
        for (int r = 0; r < 4; ++r) {
            const int e = e0 + q * 4 + r;
            if (is64) { srcs[r] = ei[2 * e]; dsts[r] = ei[2 * N_EDGES + 2 * e]; }
            else      { srcs[r] = ei[e];     dsts[r] = ei[N_EDGES + e]; }
        }
#pragma unroll
        for (int r = 0; r < 4; ++r) {
            const int s = srcs[r], d = dsts[r];
            if (s < 0 || s >= N_NODES || d < 0 || d >= N_NODES) continue;
            const float* xrow = x + (size_t)s * 96;
            float* arow = aggr + (size_t)d * 96;
#pragma unroll
            for (int f = 0; f < 6; ++f) {
                const int n = t + 16 * f;  // 16 lanes -> consecutive addrs
                float m = acc[f][r] + ben[f] + xrow[n];
                m = m > 0.f ? m : 0.f;
                atomicAdd(&arow[n], m);
            }
        }
    }
}

// ---------------------------------------------------------------------------
// mlp v2 (fp32, register-tiled): 64-node tile, 256 threads.
// thread (fg=tid&15, ng=tid>>4): 4 nodes x 6 features, 24 accumulators.
// hsT[k][n] (pad 68: bank = (4k+n)%32, conflict-free reads), Ws[96*96].
// Per k-step: 1x b128 (hsT) + 3x b64 (Ws) for 24 MACs.
// In-wave: fg = lane&15 varies -> hsT reads broadcast 16-way (free),
// Ws reads hit 16 distinct banks (checked).
// Writes o rows back into buf (disjoint rows per block; staged first).
// ---------------------------------------------------------------------------
#define MTILE 64
__global__ __launch_bounds__(256) void mlp_kernel(
    float* buf, const float* __restrict__ W1g, const float* __restrict__ b1g,
    const float* __restrict__ W2g, const float* __restrict__ b2g,
    float* __restrict__ stats) {
    __shared__ float Ws[96 * 96];
    __shared__ float hsT[96][68];

    const int tid = threadIdx.x;
    const int fg = tid & 15;
    const int ng = tid >> 4;
    const int n0 = blockIdx.x * MTILE;

    for (int i = tid; i < 96 * 96 / 4; i += 256)
        ((f32x4*)Ws)[i] = ((const f32x4*)W1g)[i];
    for (int i = tid; i < MTILE * 96 / 4; i += 256) {
        const int base = i * 4;
        const int nn = base / 96, k = base - nn * 96;
        f32x4 v = {0.f, 0.f, 0.f, 0.f};
        if (n0 + nn < N_NODES)
            v = *(const f32x4*)(buf + (size_t)(n0 + nn) * 96 + k);
        hsT[k][nn] = v[0]; hsT[k + 1][nn] = v[1];
        hsT[k + 2][nn] = v[2]; hsT[k + 3][nn] = v[3];
    }
    __syncthreads();

    float acc[4][6];
#pragma unroll
    for (int ff = 0; ff < 6; ++ff) {
        const float b = b1g[6 * fg + ff];
        acc[0][ff] = b; acc[1][ff] = b; acc[2][ff] = b; acc[3][ff] = b;
    }
    for (int k = 0; k < 96; ++k) {
        const f32x4 a = *(const f32x4*)&hsT[k][4 * ng];
        const float* wr = &Ws[k * 96 + 6 * fg];
        const f32x2 w01 = *(const f32x2*)(wr);
        const f32x2 w23 = *(const f32x2*)(wr + 2);
        const f32x2 w45 = *(const f32x2*)(wr + 4);
        const float w[6] = {w01[0], w01[1], w23[0], w23[1], w45[0], w45[1]};
#pragma unroll
        for (int nn = 0; nn < 4; ++nn)
#pragma unroll
            for (int ff = 0; ff < 6; ++ff) acc[nn][ff] += a[nn] * w[ff];
    }
    __syncthreads();  // done reading hsT/Ws

    // write hm (relu) transposed; reload Ws = W2
#pragma unroll
    for (int nn = 0; nn < 4; ++nn)
#pragma unroll
        for (int ff = 0; ff < 6; ++ff) {
            float v = acc[nn][ff];
            hsT[6 * fg + ff][4 * ng + nn] = v > 0.f ? v : 0.f;
        }
    for (int i = tid; i < 96 * 96 / 4; i += 256)
        ((f32x4*)Ws)[i] = ((const f32x4*)W2g)[i];
    __syncthreads();

#pragma unroll
    for (int ff = 0; ff < 6; ++ff) {
        const float b = b2g[6 * fg + ff];
        acc[0][ff] = b; acc[1][ff] = b; acc[2][ff] = b; acc[3][ff] = b;
    }
    for (int k = 0; k < 96; ++k) {
        const f32x4 a = *(const f32x4*)&hsT[k][4 * ng];
        const float* wr = &Ws[k * 96 + 6 * fg];
        const f32x2 w01 = *(const f32x2*)(wr);
        const f32x2 w23 = *(const f32x2*)(wr + 2);
        const f32x2 w45 = *(const f32x2*)(wr + 4);
        const float w[6] = {w01[0], w01[1], w23[0], w23[1], w45[0], w45[1]};
#pragma unroll
        for (int nn = 0; nn < 4; ++nn)
#pragma unroll
            for (int ff = 0; ff < 6; ++ff) acc[nn][ff] += a[nn] * w[ff];
    }

    // global store o from regs (coalesced-ish: 16 fg threads cover a row)
#pragma unroll
    for (int nn = 0; nn < 4; ++nn) {
        const int n = n0 + 4 * ng + nn;
        if (n < N_NODES) {
            float* o = buf + (size_t)n * 96 + 6 * fg;
            *(f32x2*)(o)     = (f32x2){acc[nn][0], acc[nn][1]};
            *(f32x2*)(o + 2) = (f32x2){acc[nn][2], acc[nn][3]};
            *(f32x2*)(o + 4) = (f32x2){acc[nn][4], acc[nn][5]};
        }
    }

    __syncthreads();  // done reading hsT (GEMM2)
#pragma unroll
    for (int nn = 0; nn < 4; ++nn)
#pragma unroll
        for (int ff = 0; ff < 6; ++ff)
            hsT[6 * fg + ff][4 * ng + nn] = acc[nn][ff];
    __syncthreads();

    if (tid < 96) {
        int nmax = N_NODES - n0;
        if (nmax > MTILE) nmax = MTILE;
        float s = 0.f, s2 = 0.f;
        for (int n = 0; n < nmax; ++n) {
            const float v = hsT[tid][n];
            s += v; s2 += v * v;
        }
        atomicAdd(&stats[tid], s);
        atomicAdd(&stats[96 + tid], s2);
    }
}

// ---------------------------------------------------------------------------
// bn v2: finalize + affine + ReLU, float4 streaming.
// ---------------------------------------------------------------------------
__global__ __launch_bounds__(256) void bn_kernel(
    const float* __restrict__ h2, const float* __restrict__ stats,
    const float* __restrict__ gamma, const float* __restrict__ beta,
    float* __restrict__ out) {
    __shared__ float sc[96], sh[96];
    const int tid = threadIdx.x;
    if (tid < 96) {
        const float inv_n = 1.f / (float)N_NODES;
        const float mean = stats[tid] * inv_n;
        float var = stats[96 + tid] * inv_n - mean * mean;
        var = var > 0.f ? var : 0.f;
        const float s = gamma[tid] * rsqrtf(var + BN_EPS);
        sc[tid] = s;
        sh[tid] = beta[tid] - mean * s;
    }
    __syncthreads();
    const int total4 = N_NODES * 96 / 4;
    for (int i = blockIdx.x * blockDim.x + tid; i < total4;
         i += gridDim.x * blockDim.x) {
        f32x4 v = ((const f32x4*)h2)[i];
        const int jb = (i * 4) % 96;
#pragma unroll
        for (int c = 0; c < 4; ++c) {
            float u = v[c] * sc[jb + c] + sh[jb + c];
            v[c] = u > 0.f ? u : 0.f;
        }
        ((f32x4*)out)[i] = v;
    }
}

// ---------------------------------------------------------------------------
extern "C" void kernel_launch(void* const* d_in, const int* in_sizes, int n_in,
                              void* d_out, int out_size, void* d_ws,
                              size_t ws_size, hipStream_t stream) {
    const float* x     = (const float*)d_in[0];
    const int*   ei    = (const int*)d_in[1];
    const float* ea    = (const float*)d_in[2];
    const float* We    = (const float*)d_in[3];
    const float* be    = (const float*)d_in[4];
    const float* W1    = (const float*)d_in[5];
    const float* b1    = (const float*)d_in[6];
    const float* W2    = (const float*)d_in[7];
    const float* b2    = (const float*)d_in[8];
    const float* gamma = (const float*)d_in[9];
    const float* beta  = (const float*)d_in[10];
    float* out = (float*)d_out;

    float* ws    = (float*)d_ws;
    float* hbuf  = ws;              // 4.8M floats: x+aggr -> o
    float* stats = ws + OFF_STATS;
    int*   flag  = (int*)(ws + OFF_FLAG);

    // hbuf <- x (so edge kernel accumulates h = x + sum(msg) in place)
    hipMemcpyAsync(hbuf, x, (size_t)N_NODES * 96 * sizeof(float),
                   hipMemcpyDeviceToDevice, stream);
    hipMemsetAsync((void*)stats, 0, 256 * sizeof(float), stream);

    detect_kernel<<<1, 1024, 0, stream>>>(ei, flag);
    edge_mfma_kernel<<<1024, 256, 0, stream>>>(x, ei, ea, We, be, hbuf, flag);
    mlp_kernel<<<(N_NODES + MTILE - 1) / MTILE, 256, 0, stream>>>(
        hbuf, W1, b1, W2, b2, stats);
    bn_kernel<<<1024, 256, 0, stream>>>(hbuf, stats, gamma, beta, out);
}